// Round 13
// baseline (267.034 us; speedup 1.0000x reference)
//
#include <hip/hip_runtime.h>

// NewSupConLoss: B=512, L=20, D=128. Full Gram N=10240, fused exp/rowsum.
// Round 13: M=128 per wave (af[4][8] persistent = 128 VGPR), 16-col slices,
// depth-2 prefetch (3x4KB buffers, vmcnt(8)) -> staging latency covered by
// ~2 compute phases; staging traffic halved vs R12. 2-wave 128-thr blocks,
// barrier-free (wave-private LDS), hoisted slice addressing.

#define NB 512
#define NL 20
#define NROW (NB * NL)            // 10240
#define FBYTES (NROW * 256)       // 2,621,440
#define SCALE 4.5398160f          // sqrt(log2(e)/0.07); dot feeds exp2 directly
#define TEMP_INV 14.285714285714286f

typedef float f32x4 __attribute__((ext_vector_type(4)));
typedef short short8 __attribute__((ext_vector_type(8)));
typedef unsigned short ushort4v __attribute__((ext_vector_type(4)));

static __device__ __forceinline__ unsigned short f2bf(float x) {
  unsigned int b = __float_as_uint(x);
  b += 0x7FFFu + ((b >> 16) & 1u);
  return (unsigned short)(b >> 16);
}

static __device__ __forceinline__ float fexp2(float x) {
#if __has_builtin(__builtin_amdgcn_exp2f)
  return __builtin_amdgcn_exp2f(x);
#else
  return exp2f(x);
#endif
}

// Blocks [0,1280): fp32 -> bf16 rows a=l*512+i, scaled, XOR-swizzled.
// Blocks [1280,1600): gp[c][grp][d] partial g-sums (16 independent loads).
__global__ __launch_bounds__(256) void k_prep(const float* __restrict__ feat,
                                              const int* __restrict__ labels,
                                              unsigned char* __restrict__ fswz,
                                              float* __restrict__ gp) {
  const int b = blockIdx.x;
  if (b < 1280) {
    int t = b * 256 + threadIdx.x;   // [0, 327680)
    int q = t & 31;
    int a = t >> 5;
    int l = a >> 9;
    int i = a & 511;
    const float* src = feat + (size_t)i * (NL * 128) + l * 128 + q * 4;
    float4 v = *(const float4*)src;
    ushort4v u;
    u.x = f2bf(v.x * SCALE); u.y = f2bf(v.y * SCALE);
    u.z = f2bf(v.z * SCALE); u.w = f2bf(v.w * SCALE);
    int dst = a * 256 + ((q * 8) ^ ((a & 7) << 4));
    *(ushort4v*)(fswz + dst) = u;
  } else {
    __shared__ float part[2][128];
    const int idx = b - 1280;          // [0,320)
    const int c = idx >> 4, grp = idx & 15;
    const int d = threadIdx.x & 127, half = threadIdx.x >> 7;
    const int i0 = grp * 32 + half * 16;
    float s = 0.f;
#pragma unroll
    for (int k = 0; k < 16; ++k) {     // independent load pairs, latency-hidden
      int i = i0 + k;
      s += (float)labels[i * NL + c] * feat[(size_t)i * (NL * 128) + c * 128 + d];
    }
    part[half][d] = s;
    __syncthreads();
    if (half == 0) gp[(c * 16 + grp) * 128 + d] = part[0][d] + part[1][d];
  }
}

// Pr[c][h][sr][r] : partial row-sums of exp over 256 cols (class c, half h).
// Grid (80 sr2, 20 c) x 128 thr. Wave w = col half h; rows [sr2*128,+128).
__global__ void k_gram(const unsigned char* __restrict__ fswz,
                       float* __restrict__ Pr) {
  __shared__ unsigned char lds[24576];   // 2 waves x (three 4KB slice buffers)
  const int sr2 = blockIdx.x;            // 128-row strip [sr2*128,+128)
  const int c = blockIdx.y;              // class
  const int tid = threadIdx.x;
  const int lane = tid & 63;
  const int h = tid >> 6;                // wave = col half
  const int fr = lane & 15, kg = lane >> 4;
  const int xr = (fr & 7) << 4;
  unsigned char* myl = lds + h * 12288;  // wave-private, wave-uniform base

  // ---- persistent A fragments: 32 x short8 = 128 VGPR ----
  short8 af[4][8];   // [kk][m], m over 8 x 16-row blocks
#pragma unroll
  for (int kk = 0; kk < 4; ++kk)
#pragma unroll
    for (int m = 0; m < 8; ++m)
      af[kk][m] = *(const short8*)(fswz + (size_t)(sr2 * 128 + m * 16 + fr) * 256 +
                                   ((kk * 64 + kg * 16) ^ xr));

  // hoisted staging addresses: global ptr advances 4096/slice; 3 LDS bufs
  const unsigned char* gB = fswz + ((size_t)c * 512 + h * 256) * 256 + lane * 16;
  auto stage = [&](int buf, int t) {     // slice t: 16 Gram-cols = 4KB
    const unsigned char* g = gB + t * 4096;
    unsigned char* lb = myl + buf * 4096 + lane * 16;
#pragma unroll
    for (int p = 0; p < 4; ++p)
      __builtin_amdgcn_global_load_lds(
          (const __attribute__((address_space(1))) unsigned int*)(g + p * 1024),
          (__attribute__((address_space(3))) unsigned int*)(lb + p * 1024), 16, 0, 0);
  };

  stage(0, 0);
  stage(1, 1);
  float esum[8][4] = {};   // [m][reg]

  // diag (i==j): slice t carries diag rows iff md = h*16 + t - (sr2&3)*8 in [0,8);
  // then mask at m == md, lane kg*4+reg == fr.
  const int mdbase = h * 16 - (sr2 & 3) * 8;
  int bi = 0;

  for (int t = 0; t < 16; ++t) {
    asm volatile("" ::: "memory");   // keep stage below prior ds_reads
    if (t < 14) {
      int nb = bi + 2; if (nb >= 3) nb -= 3;
      stage(nb, t + 2);
      asm volatile("s_waitcnt vmcnt(8)" ::: "memory");   // slice t resident
    } else if (t < 15) {
      asm volatile("s_waitcnt vmcnt(4)" ::: "memory");
    } else {
      asm volatile("s_waitcnt vmcnt(0)" ::: "memory");
    }

    const unsigned char* lb = myl + bi * 4096;
    f32x4 acc[8] = {};   // 128 rows x 16 cols
#pragma unroll
    for (int kk = 0; kk < 4; ++kk) {
      short8 bf = *(const short8*)(lb + fr * 256 + ((kk * 64 + kg * 16) ^ xr));
#pragma unroll
      for (int m = 0; m < 8; ++m)
        acc[m] = __builtin_amdgcn_mfma_f32_16x16x32_bf16(af[kk][m], bf, acc[m], 0, 0, 0);
    }

    // ---- epilogue: exp + accumulate; mask only on the 8 diag slices ----
    const int md = mdbase + t;
    if (md >= 0 && md < 8) {
#pragma unroll
      for (int m = 0; m < 8; ++m)
#pragma unroll
        for (int reg = 0; reg < 4; ++reg) {
          float ex = fexp2(acc[m][reg]);
          if (m == md && (kg * 4 + reg) == fr) ex = 0.f;
          esum[m][reg] += ex;
        }
    } else {
#pragma unroll
      for (int m = 0; m < 8; ++m)
#pragma unroll
        for (int reg = 0; reg < 4; ++reg)
          esum[m][reg] += fexp2(acc[m][reg]);
    }
    if (++bi == 3) bi = 0;
  }

  // ---- flush once: reduce over fr (16 cols) + plain stores ----
#pragma unroll
  for (int m = 0; m < 8; ++m)
#pragma unroll
    for (int reg = 0; reg < 4; ++reg) {
      float e = esum[m][reg];
      e += __shfl_xor(e, 1, 64); e += __shfl_xor(e, 2, 64);
      e += __shfl_xor(e, 4, 64); e += __shfl_xor(e, 8, 64);
      if (fr == 0) {
        const int sr = sr2 * 2 + (m >> 2);               // 64-row index
        const int r = (m & 3) * 16 + kg * 4 + reg;       // row within 64
        Pr[(((size_t)c * 2 + h) * 160 + sr) * 64 + r] = e;
      }
    }
}

// Blocks [0,2560): wnum (wave per (c,i), folds 16 gp partials, coalesced).
// Blocks [2560,2600): Slog = log(sum of 40 Pr partials), coalesced.
__global__ __launch_bounds__(256) void k_ws(const float* __restrict__ Pr,
                                            const float* __restrict__ feat,
                                            const float* __restrict__ gp,
                                            float* __restrict__ Slog,
                                            float* __restrict__ wnum) {
  const int b = blockIdx.x;
  if (b < 2560) {
    const int lane = threadIdx.x & 63;
    const int p = b * 4 + (threadIdx.x >> 6);   // pair c*512+i
    const int c = p >> 9, i = p & 511;
    float2 f = *(const float2*)(feat + (size_t)i * (NL * 128) + c * 128 + lane * 2);
    float gx = 0.f, gy = 0.f;
#pragma unroll
    for (int q = 0; q < 16; ++q) {
      float2 g2 = *(const float2*)(gp + (c * 16 + q) * 128 + lane * 2);
      gx += g2.x; gy += g2.y;
    }
    float v = f.x * gx + f.y * gy;
#pragma unroll
    for (int sh = 1; sh < 64; sh <<= 1) v += __shfl_xor(v, sh, 64);
    if (lane == 0) wnum[p] = (v - 1.f) * TEMP_INV;   // self term f.f==1 removed
  } else {
    int idx = (b - 2560) * 256 + threadIdx.x;   // [0, 10240)
    int c = idx >> 9, i = idx & 511;
    float s = 0.f;
#pragma unroll
    for (int l2 = 0; l2 < NL; ++l2) {
      const float* p2 = Pr + (((size_t)c * 2) * 160 + l2 * 8 + (i >> 6)) * 64 + (i & 63);
      s += p2[0] + p2[160 * 64];
    }
    Slog[idx] = logf(s);
  }
}

// Per-anchor combine + mean. One block, 512 threads.
__global__ __launch_bounds__(512) void k_final(const float* __restrict__ Slog,
                                               const float* __restrict__ wnum,
                                               const int* __restrict__ labels,
                                               float* __restrict__ out) {
  __shared__ float cnt[NL];
  __shared__ float red[8];
  const int i = threadIdx.x;
  if (i < NL) cnt[i] = 0.f;
  __syncthreads();
  int lab[NL];
#pragma unroll
  for (int cI = 0; cI < NL; ++cI) lab[cI] = labels[i * NL + cI];
#pragma unroll
  for (int cI = 0; cI < NL; ++cI)
    if (lab[cI]) atomicAdd(&cnt[cI], 1.f);
  __syncthreads();
  float avg = 0.f, acc = 0.f;
#pragma unroll
  for (int cI = 0; cI < NL; ++cI) {
    if (lab[cI]) {
      float wgt = cnt[cI] - 1.f;
      avg += wgt;
      acc += wnum[cI * NB + i] - wgt * Slog[cI * NB + i];
    }
  }
  float v = acc / (avg == 0.f ? 1.f : avg);
#pragma unroll
  for (int s = 1; s < 64; s <<= 1) v += __shfl_xor(v, s, 64);
  if ((i & 63) == 0) red[i >> 6] = v;
  __syncthreads();
  if (i == 0) {
    float tot = 0.f;
#pragma unroll
    for (int k = 0; k < 8; ++k) tot += red[k];
    out[0] = -(tot / (float)NB);
  }
}

extern "C" void kernel_launch(void* const* d_in, const int* in_sizes, int n_in,
                              void* d_out, int out_size, void* d_ws, size_t ws_size,
                              hipStream_t stream) {
  const float* feat = (const float*)d_in[0];
  const int* labels = (const int*)d_in[1];
  float* out = (float*)d_out;
  unsigned char* ws = (unsigned char*)d_ws;
  unsigned char* fswz = ws;                          // 2,621,440 B
  float* Pr = (float*)(ws + FBYTES);                 // 20*2*160*64 f32 = 1.6 MB
  float* gp = Pr + 20 * 2 * 160 * 64;                // 320*128 f32
  float* Slog = gp + 320 * 128;                      // 10240 f32
  float* wnum = Slog + NROW;                         // 10240 f32

  k_prep<<<1600, 256, 0, stream>>>(feat, labels, fswz, gp);
  dim3 grid(80, 20);
  k_gram<<<grid, 128, 0, stream>>>(fswz, Pr);
  k_ws<<<2600, 256, 0, stream>>>(Pr, feat, gp, Slog, wnum);
  k_final<<<1, 512, 0, stream>>>(Slog, wnum, labels, out);
}

// Round 14
// 92.315 us; speedup vs baseline: 2.8927x; 2.8927x over previous
//
#include <hip/hip_runtime.h>

// NewSupConLoss: B=512, L=20, D=128. Full Gram N=10240, fused exp/rowsum.
// Round 14: R13 (M=128/wave, af[4][8] persistent, depth-2 prefetch, 3x4KB
// LDS, barrier-free) + THE FIX: __launch_bounds__(128,1) so the allocator
// may use up to 512 VGPRs (R13 omitted it -> 64-VGPR cap -> af spilled,
// 546MB scratch FETCH, 260us).

#define NB 512
#define NL 20
#define NROW (NB * NL)            // 10240
#define FBYTES (NROW * 256)       // 2,621,440
#define SCALE 4.5398160f          // sqrt(log2(e)/0.07); dot feeds exp2 directly
#define TEMP_INV 14.285714285714286f

typedef float f32x4 __attribute__((ext_vector_type(4)));
typedef short short8 __attribute__((ext_vector_type(8)));
typedef unsigned short ushort4v __attribute__((ext_vector_type(4)));

static __device__ __forceinline__ unsigned short f2bf(float x) {
  unsigned int b = __float_as_uint(x);
  b += 0x7FFFu + ((b >> 16) & 1u);
  return (unsigned short)(b >> 16);
}

static __device__ __forceinline__ float fexp2(float x) {
#if __has_builtin(__builtin_amdgcn_exp2f)
  return __builtin_amdgcn_exp2f(x);
#else
  return exp2f(x);
#endif
}

// Blocks [0,1280): fp32 -> bf16 rows a=l*512+i, scaled, XOR-swizzled.
// Blocks [1280,1600): gp[c][grp][d] partial g-sums (16 independent loads).
__global__ __launch_bounds__(256) void k_prep(const float* __restrict__ feat,
                                              const int* __restrict__ labels,
                                              unsigned char* __restrict__ fswz,
                                              float* __restrict__ gp) {
  const int b = blockIdx.x;
  if (b < 1280) {
    int t = b * 256 + threadIdx.x;   // [0, 327680)
    int q = t & 31;
    int a = t >> 5;
    int l = a >> 9;
    int i = a & 511;
    const float* src = feat + (size_t)i * (NL * 128) + l * 128 + q * 4;
    float4 v = *(const float4*)src;
    ushort4v u;
    u.x = f2bf(v.x * SCALE); u.y = f2bf(v.y * SCALE);
    u.z = f2bf(v.z * SCALE); u.w = f2bf(v.w * SCALE);
    int dst = a * 256 + ((q * 8) ^ ((a & 7) << 4));
    *(ushort4v*)(fswz + dst) = u;
  } else {
    __shared__ float part[2][128];
    const int idx = b - 1280;          // [0,320)
    const int c = idx >> 4, grp = idx & 15;
    const int d = threadIdx.x & 127, half = threadIdx.x >> 7;
    const int i0 = grp * 32 + half * 16;
    float s = 0.f;
#pragma unroll
    for (int k = 0; k < 16; ++k) {     // independent load pairs, latency-hidden
      int i = i0 + k;
      s += (float)labels[i * NL + c] * feat[(size_t)i * (NL * 128) + c * 128 + d];
    }
    part[half][d] = s;
    __syncthreads();
    if (half == 0) gp[(c * 16 + grp) * 128 + d] = part[0][d] + part[1][d];
  }
}

// Pr[c][h][sr][r] : partial row-sums of exp over 256 cols (class c, half h).
// Grid (80 sr2, 20 c) x 128 thr. Wave w = col half h; rows [sr2*128,+128).
__global__ __launch_bounds__(128, 1) void k_gram(const unsigned char* __restrict__ fswz,
                                                 float* __restrict__ Pr) {
  __shared__ unsigned char lds[24576];   // 2 waves x (three 4KB slice buffers)
  const int sr2 = blockIdx.x;            // 128-row strip [sr2*128,+128)
  const int c = blockIdx.y;              // class
  const int tid = threadIdx.x;
  const int lane = tid & 63;
  const int h = tid >> 6;                // wave = col half
  const int fr = lane & 15, kg = lane >> 4;
  const int xr = (fr & 7) << 4;
  unsigned char* myl = lds + h * 12288;  // wave-private, wave-uniform base

  // ---- persistent A fragments: 32 x short8 = 128 VGPR ----
  short8 af[4][8];   // [kk][m], m over 8 x 16-row blocks
#pragma unroll
  for (int kk = 0; kk < 4; ++kk)
#pragma unroll
    for (int m = 0; m < 8; ++m)
      af[kk][m] = *(const short8*)(fswz + (size_t)(sr2 * 128 + m * 16 + fr) * 256 +
                                   ((kk * 64 + kg * 16) ^ xr));

  // hoisted staging addresses: global ptr advances 4096/slice; 3 LDS bufs
  const unsigned char* gB = fswz + ((size_t)c * 512 + h * 256) * 256 + lane * 16;
  auto stage = [&](int buf, int t) {     // slice t: 16 Gram-cols = 4KB
    const unsigned char* g = gB + t * 4096;
    unsigned char* lb = myl + buf * 4096 + lane * 16;
#pragma unroll
    for (int p = 0; p < 4; ++p)
      __builtin_amdgcn_global_load_lds(
          (const __attribute__((address_space(1))) unsigned int*)(g + p * 1024),
          (__attribute__((address_space(3))) unsigned int*)(lb + p * 1024), 16, 0, 0);
  };

  stage(0, 0);
  stage(1, 1);
  float esum[8][4] = {};   // [m][reg]

  // diag (i==j): slice t carries diag rows iff md = h*16 + t - (sr2&3)*8 in [0,8);
  // then mask at m == md, lane kg*4+reg == fr.
  const int mdbase = h * 16 - (sr2 & 3) * 8;
  int bi = 0;

  for (int t = 0; t < 16; ++t) {
    asm volatile("" ::: "memory");   // keep stage below prior ds_reads
    if (t < 14) {
      int nb = bi + 2; if (nb >= 3) nb -= 3;
      stage(nb, t + 2);
      asm volatile("s_waitcnt vmcnt(8)" ::: "memory");   // slice t resident
    } else if (t < 15) {
      asm volatile("s_waitcnt vmcnt(4)" ::: "memory");
    } else {
      asm volatile("s_waitcnt vmcnt(0)" ::: "memory");
    }

    const unsigned char* lb = myl + bi * 4096;
    f32x4 acc[8] = {};   // 128 rows x 16 cols
#pragma unroll
    for (int kk = 0; kk < 4; ++kk) {
      short8 bf = *(const short8*)(lb + fr * 256 + ((kk * 64 + kg * 16) ^ xr));
#pragma unroll
      for (int m = 0; m < 8; ++m)
        acc[m] = __builtin_amdgcn_mfma_f32_16x16x32_bf16(af[kk][m], bf, acc[m], 0, 0, 0);
    }

    // ---- epilogue: exp + accumulate; mask only on the 8 diag slices ----
    const int md = mdbase + t;
    if (md >= 0 && md < 8) {
#pragma unroll
      for (int m = 0; m < 8; ++m)
#pragma unroll
        for (int reg = 0; reg < 4; ++reg) {
          float ex = fexp2(acc[m][reg]);
          if (m == md && (kg * 4 + reg) == fr) ex = 0.f;
          esum[m][reg] += ex;
        }
    } else {
#pragma unroll
      for (int m = 0; m < 8; ++m)
#pragma unroll
        for (int reg = 0; reg < 4; ++reg)
          esum[m][reg] += fexp2(acc[m][reg]);
    }
    if (++bi == 3) bi = 0;
  }

  // ---- flush once: reduce over fr (16 cols) + plain stores ----
#pragma unroll
  for (int m = 0; m < 8; ++m)
#pragma unroll
    for (int reg = 0; reg < 4; ++reg) {
      float e = esum[m][reg];
      e += __shfl_xor(e, 1, 64); e += __shfl_xor(e, 2, 64);
      e += __shfl_xor(e, 4, 64); e += __shfl_xor(e, 8, 64);
      if (fr == 0) {
        const int sr = sr2 * 2 + (m >> 2);               // 64-row index
        const int r = (m & 3) * 16 + kg * 4 + reg;       // row within 64
        Pr[(((size_t)c * 2 + h) * 160 + sr) * 64 + r] = e;
      }
    }
}

// Blocks [0,2560): wnum (wave per (c,i), folds 16 gp partials, coalesced).
// Blocks [2560,2600): Slog = log(sum of 40 Pr partials), coalesced.
__global__ __launch_bounds__(256) void k_ws(const float* __restrict__ Pr,
                                            const float* __restrict__ feat,
                                            const float* __restrict__ gp,
                                            float* __restrict__ Slog,
                                            float* __restrict__ wnum) {
  const int b = blockIdx.x;
  if (b < 2560) {
    const int lane = threadIdx.x & 63;
    const int p = b * 4 + (threadIdx.x >> 6);   // pair c*512+i
    const int c = p >> 9, i = p & 511;
    float2 f = *(const float2*)(feat + (size_t)i * (NL * 128) + c * 128 + lane * 2);
    float gx = 0.f, gy = 0.f;
#pragma unroll
    for (int q = 0; q < 16; ++q) {
      float2 g2 = *(const float2*)(gp + (c * 16 + q) * 128 + lane * 2);
      gx += g2.x; gy += g2.y;
    }
    float v = f.x * gx + f.y * gy;
#pragma unroll
    for (int sh = 1; sh < 64; sh <<= 1) v += __shfl_xor(v, sh, 64);
    if (lane == 0) wnum[p] = (v - 1.f) * TEMP_INV;   // self term f.f==1 removed
  } else {
    int idx = (b - 2560) * 256 + threadIdx.x;   // [0, 10240)
    int c = idx >> 9, i = idx & 511;
    float s = 0.f;
#pragma unroll
    for (int l2 = 0; l2 < NL; ++l2) {
      const float* p2 = Pr + (((size_t)c * 2) * 160 + l2 * 8 + (i >> 6)) * 64 + (i & 63);
      s += p2[0] + p2[160 * 64];
    }
    Slog[idx] = logf(s);
  }
}

// Per-anchor combine + mean. One block, 512 threads.
__global__ __launch_bounds__(512) void k_final(const float* __restrict__ Slog,
                                               const float* __restrict__ wnum,
                                               const int* __restrict__ labels,
                                               float* __restrict__ out) {
  __shared__ float cnt[NL];
  __shared__ float red[8];
  const int i = threadIdx.x;
  if (i < NL) cnt[i] = 0.f;
  __syncthreads();
  int lab[NL];
#pragma unroll
  for (int cI = 0; cI < NL; ++cI) lab[cI] = labels[i * NL + cI];
#pragma unroll
  for (int cI = 0; cI < NL; ++cI)
    if (lab[cI]) atomicAdd(&cnt[cI], 1.f);
  __syncthreads();
  float avg = 0.f, acc = 0.f;
#pragma unroll
  for (int cI = 0; cI < NL; ++cI) {
    if (lab[cI]) {
      float wgt = cnt[cI] - 1.f;
      avg += wgt;
      acc += wnum[cI * NB + i] - wgt * Slog[cI * NB + i];
    }
  }
  float v = acc / (avg == 0.f ? 1.f : avg);
#pragma unroll
  for (int s = 1; s < 64; s <<= 1) v += __shfl_xor(v, s, 64);
  if ((i & 63) == 0) red[i >> 6] = v;
  __syncthreads();
  if (i == 0) {
    float tot = 0.f;
#pragma unroll
    for (int k = 0; k < 8; ++k) tot += red[k];
    out[0] = -(tot / (float)NB);
  }
}

extern "C" void kernel_launch(void* const* d_in, const int* in_sizes, int n_in,
                              void* d_out, int out_size, void* d_ws, size_t ws_size,
                              hipStream_t stream) {
  const float* feat = (const float*)d_in[0];
  const int* labels = (const int*)d_in[1];
  float* out = (float*)d_out;
  unsigned char* ws = (unsigned char*)d_ws;
  unsigned char* fswz = ws;                          // 2,621,440 B
  float* Pr = (float*)(ws + FBYTES);                 // 20*2*160*64 f32 = 1.6 MB
  float* gp = Pr + 20 * 2 * 160 * 64;                // 320*128 f32
  float* Slog = gp + 320 * 128;                      // 10240 f32
  float* wnum = Slog + NROW;                         // 10240 f32

  k_prep<<<1600, 256, 0, stream>>>(feat, labels, fswz, gp);
  dim3 grid(80, 20);
  k_gram<<<grid, 128, 0, stream>>>(fswz, Pr);
  k_ws<<<2600, 256, 0, stream>>>(Pr, feat, gp, Slog, wnum);
  k_final<<<1, 512, 0, stream>>>(Slog, wnum, labels, out);
}